// Round 1
// baseline (1152.139 us; speedup 1.0000x reference)
//
#include <hip/hip_runtime.h>
#include <math.h>

typedef __attribute__((ext_vector_type(8))) short short8;
typedef __attribute__((ext_vector_type(4))) float floatx4;

constexpr int kB  = 64;    // batch
constexpr int kP  = 50;    // nodes per graph
constexpr int kE  = 400;   // edges per graph
constexpr int kF1 = 128;   // GCN feature dim (2H)
constexpr int kH  = 64;    // H
constexpr int kNT = 2000;  // head output per sample
constexpr int kNEDGE = kE + kP;  // incl. self loops

__device__ __forceinline__ unsigned short f2bf(float f) {
    union { float f; unsigned u; } v; v.f = f;
    unsigned u = v.u;
    u += 0x7fffu + ((u >> 16) & 1u);   // RNE
    return (unsigned short)(u >> 16);
}

__device__ __forceinline__ float leakyf(float v) { return v >= 0.f ? v : 0.01f * v; }

// C[M,N] (+)= A[M,K] @ W[K,N]; bf16 MFMA 16x16x32, fp32 accumulate.
// grid (N/64, M/64, splitk), block 256. kchunk = K/splitk (multiple of 32).
__global__ __launch_bounds__(256) void gemm_bf16(
    const float* __restrict__ A, const float* __restrict__ W, float* __restrict__ C,
    int Mr, int N, int K, int kchunk)
{
    // stride 40 shorts (80 B) keeps 16B alignment for b128 frag reads and breaks
    // the worst power-of-2 bank patterns. Staging conflicts are noise: we have
    // ~20x compute headroom vs the HBM roofline here.
    __shared__ unsigned short lds_a[64 * 40];
    __shared__ unsigned short lds_w[64 * 40];

    const int t  = threadIdx.x;
    const int n0 = blockIdx.x * 64;
    const int m0 = blockIdx.y * 64;
    const int k0 = blockIdx.z * kchunk;
    const int kend = k0 + kchunk;
    const bool accumulate = (gridDim.z > 1);

    const int ar = t >> 2;            // A stage: row 0..63
    const int ac = (t & 3) * 8;       // A stage: k offset 0/8/16/24
    const int wc = t & 63;            // W stage: col 0..63
    const int wr = (t >> 6) * 8;      // W stage: k offset 0/8/16/24

    const int wave = t >> 6;
    const int lane = t & 63;
    const int lrow = lane & 15;
    const int quad = lane >> 4;

    floatx4 acc[4];
#pragma unroll
    for (int c = 0; c < 4; ++c) acc[c] = (floatx4)0.f;

    for (int kk = k0; kk < kend; kk += 32) {
        {   // stage A tile 64x32 -> bf16
            const float4* ap = reinterpret_cast<const float4*>(
                &A[(size_t)(m0 + ar) * K + kk + ac]);
            float4 v0 = ap[0], v1 = ap[1];
            unsigned short* dst = &lds_a[ar * 40 + ac];
            dst[0] = f2bf(v0.x); dst[1] = f2bf(v0.y);
            dst[2] = f2bf(v0.z); dst[3] = f2bf(v0.w);
            dst[4] = f2bf(v1.x); dst[5] = f2bf(v1.y);
            dst[6] = f2bf(v1.z); dst[7] = f2bf(v1.w);
        }
        {   // stage W tile 32x64 transposed -> lds_w[col][k]
            unsigned short* dst = &lds_w[wc * 40 + wr];
#pragma unroll
            for (int i = 0; i < 8; ++i)
                dst[i] = f2bf(W[(size_t)(kk + wr + i) * N + n0 + wc]);
        }
        __syncthreads();
        // A frag: A[m = lane&15][k = quad*8+j]; wave handles rows wave*16..+15
        short8 af = *reinterpret_cast<const short8*>(
            &lds_a[(wave * 16 + lrow) * 40 + quad * 8]);
#pragma unroll
        for (int c = 0; c < 4; ++c) {
            // B frag: B[k = quad*8+j][n = lane&15], read from transposed LDS
            short8 bf = *reinterpret_cast<const short8*>(
                &lds_w[(c * 16 + lrow) * 40 + quad * 8]);
            acc[c] = __builtin_amdgcn_mfma_f32_16x16x32_bf16(af, bf, acc[c], 0, 0, 0);
        }
        __syncthreads();
    }

    // C/D layout: col = lane&15, row = quad*4 + reg  [verified m89/m91]
#pragma unroll
    for (int c = 0; c < 4; ++c) {
#pragma unroll
        for (int r = 0; r < 4; ++r) {
            int row = m0 + wave * 16 + quad * 4 + r;
            int col = n0 + c * 16 + lrow;
            float v = acc[c][r];
            if (accumulate) atomicAdd(&C[(size_t)row * N + col], v);
            else            C[(size_t)row * N + col] = v;
        }
    }
}

__global__ __launch_bounds__(256) void bias_act_k(
    float* __restrict__ C, const float* __restrict__ bias, int total, int N, int do_leaky)
{
    int i = blockIdx.x * 256 + threadIdx.x;
    if (i >= total) return;
    float v = C[i] + bias[i % N];
    if (do_leaky) v = leakyf(v);
    C[i] = v;
}

// Per-sample GCN aggregation: out[dst] += h[src]*norm; + bias; leaky.
// Also computes degree (incl self loops), dinv, norm. One block per sample.
__global__ __launch_bounds__(256) void gcn_agg(
    const float* __restrict__ hpre, const int* __restrict__ ei,
    const float* __restrict__ bias, float* __restrict__ out)
{
    __shared__ float s_agg[kP * kF1];
    __shared__ float s_deg[kP];
    __shared__ float s_dinv[kP];
    __shared__ int   s_src[kNEDGE];
    __shared__ int   s_dst[kNEDGE];
    __shared__ float s_norm[kNEDGE];

    const int s = blockIdx.x;
    const int t = threadIdx.x;

    for (int i = t; i < kP * kF1; i += 256) s_agg[i] = 0.f;
    if (t < kP) s_deg[t] = 0.f;
    __syncthreads();

    for (int e = t; e < kE; e += 256) {
        int src = ei[(size_t)s * 2 * kE + e];
        int dst = ei[(size_t)s * 2 * kE + kE + e];
        s_src[e] = src; s_dst[e] = dst;
        atomicAdd(&s_deg[dst], 1.f);
    }
    if (t < kP) {          // self loops
        s_src[kE + t] = t; s_dst[kE + t] = t;
        atomicAdd(&s_deg[t], 1.f);
    }
    __syncthreads();
    if (t < kP) s_dinv[t] = rsqrtf(s_deg[t]);   // deg >= 1 (self loop)
    __syncthreads();
    for (int e = t; e < kNEDGE; e += 256)
        s_norm[e] = s_dinv[s_src[e]] * s_dinv[s_dst[e]];
    __syncthreads();

    const int f    = t & 127;
    const int half = t >> 7;
    for (int e = half; e < kNEDGE; e += 2) {
        float v = hpre[((size_t)s * kP + s_src[e]) * kF1 + f] * s_norm[e];
        atomicAdd(&s_agg[s_dst[e] * kF1 + f], v);
    }
    __syncthreads();

    for (int i = t; i < kP * kF1; i += 256)
        out[(size_t)s * kP * kF1 + i] = leakyf(s_agg[i] + bias[i & 127]);
}

// Per-sample head: mean-pool -> leaky(Wf1) -> Wf2 -> cumsum(1000 rows x 2) -> sigmoid
__global__ __launch_bounds__(256) void head_k(
    const float* __restrict__ a2, const float* __restrict__ Wf1,
    const float* __restrict__ bf1, const float* __restrict__ Wf2,
    const float* __restrict__ bf2, float* __restrict__ out)
{
    __shared__ float s_pool[kF1];
    __shared__ float s_z[kH];
    __shared__ float s_t[kNT];
    __shared__ float ps0[256], ps1[256];

    const int s = blockIdx.x;
    const int t = threadIdx.x;

    if (t < kF1) {
        float acc = 0.f;
        for (int p = 0; p < kP; ++p)
            acc += a2[((size_t)s * kP + p) * kF1 + t];
        s_pool[t] = acc * (1.f / kP);
    }
    __syncthreads();
    if (t < kH) {
        float acc = bf1[t];
        for (int k = 0; k < kF1; ++k)
            acc += s_pool[k] * Wf1[k * kH + t];
        s_z[t] = leakyf(acc);
    }
    __syncthreads();
    for (int c = t; c < kNT; c += 256) {
        float acc = bf2[c];
        for (int k = 0; k < kH; ++k)
            acc += s_z[k] * Wf2[(size_t)k * kNT + c];
        s_t[c] = acc;
    }
    __syncthreads();

    // inclusive cumsum over 1000 rows, 2 independent chains
    float l0 = 0.f, l1 = 0.f;
    const int r0 = t * 4;
    if (r0 < 1000) {
#pragma unroll
        for (int i = 0; i < 4; ++i) {
            l0 += s_t[(r0 + i) * 2];
            l1 += s_t[(r0 + i) * 2 + 1];
        }
    }
    ps0[t] = l0; ps1[t] = l1;
    __syncthreads();
    for (int off = 1; off < 256; off <<= 1) {
        float v0 = (t >= off) ? ps0[t - off] : 0.f;
        float v1 = (t >= off) ? ps1[t - off] : 0.f;
        __syncthreads();
        ps0[t] += v0; ps1[t] += v1;
        __syncthreads();
    }
    if (r0 < 1000) {
        float run0 = ps0[t] - l0;   // exclusive prefix (exact 0 for t=0: row 0 is
        float run1 = ps1[t] - l1;   // the only row that matters at full precision)
        #pragma unroll
        for (int i = 0; i < 4; ++i) {
            run0 += s_t[(r0 + i) * 2];
            run1 += s_t[(r0 + i) * 2 + 1];
            out[(size_t)s * kNT + (r0 + i) * 2]     = 1.f / (1.f + expf(-run0));
            out[(size_t)s * kNT + (r0 + i) * 2 + 1] = 1.f / (1.f + expf(-run1));
        }
    }
}

extern "C" void kernel_launch(void* const* d_in, const int* in_sizes, int n_in,
                              void* d_out, int out_size, void* d_ws, size_t ws_size,
                              hipStream_t stream)
{
    const float* x   = (const float*)d_in[0];   // b: (64, 25600)
    const int*   ei  = (const int*)d_in[1];     // (64, 2, 400)
    const float* W1  = (const float*)d_in[2];
    const float* b1  = (const float*)d_in[3];
    const float* W2  = (const float*)d_in[4];
    const float* b2  = (const float*)d_in[5];
    const float* W3  = (const float*)d_in[6];
    const float* b3  = (const float*)d_in[7];
    const float* Wc1 = (const float*)d_in[8];
    const float* bc1 = (const float*)d_in[9];
    const float* Wc2 = (const float*)d_in[10];
    const float* bc2 = (const float*)d_in[11];
    const float* Wf1 = (const float*)d_in[12];
    const float* bf1 = (const float*)d_in[13];
    const float* Wf2 = (const float*)d_in[14];
    const float* bf2 = (const float*)d_in[15];
    float* out = (float*)d_out;

    // workspace layout (floats); total 3,072,000 floats = 12.3 MB
    float* ws    = (float*)d_ws;
    float* h1    = ws;                 // 64*3200
    float* h2    = h1 + 204800;        // 64*6400
    float* nodes = h2 + 409600;        // 64*12800 = (3200, 256)
    float* g1    = nodes + 819200;     // 3200*128
    float* a1    = g1 + 409600;
    float* g2    = a1 + 409600;
    float* a2    = g2 + 409600;

    // zero split-K atomic accumulators
    hipMemsetAsync(h1, 0, 204800 * sizeof(float), stream);
    hipMemsetAsync(h2, 0, 409600 * sizeof(float), stream);
    hipMemsetAsync(nodes, 0, 819200 * sizeof(float), stream);

    // encoder: x(64,25600) -> h1(64,3200) -> h2(64,6400) -> nodes(64,12800)
    gemm_bf16<<<dim3(3200 / 64, 1, 16), 256, 0, stream>>>(x,  W1, h1,    64, 3200, 25600, 1600);
    bias_act_k<<<(64 * 3200 + 255) / 256, 256, 0, stream>>>(h1, b1, 64 * 3200, 3200, 1);
    gemm_bf16<<<dim3(6400 / 64, 1, 8), 256, 0, stream>>>(h1, W2, h2,    64, 6400, 3200, 400);
    bias_act_k<<<(64 * 6400 + 255) / 256, 256, 0, stream>>>(h2, b2, 64 * 6400, 6400, 1);
    gemm_bf16<<<dim3(12800 / 64, 1, 8), 256, 0, stream>>>(h2, W3, nodes, 64, 12800, 6400, 800);
    bias_act_k<<<(64 * 12800 + 255) / 256, 256, 0, stream>>>(nodes, b3, 64 * 12800, 12800, 0);

    // GCN (batched GEMM across samples + per-sample aggregation)
    gemm_bf16<<<dim3(2, 50, 1), 256, 0, stream>>>(nodes, Wc1, g1, 3200, 128, 256, 256);
    gcn_agg<<<64, 256, 0, stream>>>(g1, ei, bc1, a1);
    gemm_bf16<<<dim3(2, 50, 1), 256, 0, stream>>>(a1, Wc2, g2, 3200, 128, 128, 128);
    gcn_agg<<<64, 256, 0, stream>>>(g2, ei, bc2, a2);

    // head + cumsum + sigmoid
    head_k<<<64, 256, 0, stream>>>(a2, Wf1, bf1, Wf2, bf2, out);
}